// Round 8
// baseline (396.740 us; speedup 1.0000x reference)
//
#include <hip/hip_runtime.h>

#define EMB 64
#define NBMAX 512      // max buckets (NB = ceil(N/512) = 293 for N=150000)
#define BCAP 8192      // bucket edge capacity (mean 6827, +16 sigma)
#define BSTRIDE 12288  // padded bucket region: BCAP + 512 nodes * 8 pad slots
#define NSLICE 8       // dim slices (8 dims = 16 B per node-slice), slice -> XCD

// ---------------- bf16 helpers ----------------

__device__ __forceinline__ unsigned short f2bf(float f) {   // round-to-nearest-even
    union { float f; unsigned u; } c; c.f = f;
    unsigned r = c.u + 0x7fffu + ((c.u >> 16) & 1u);
    return (unsigned short)(r >> 16);
}
__device__ __forceinline__ float bflo(unsigned u) {         // low bf16 -> f32
    union { unsigned u; float f; } c; c.u = u << 16; return c.f;
}
__device__ __forceinline__ float bfhi(unsigned u) {         // high bf16 -> f32
    union { unsigned u; float f; } c; c.u = u & 0xffff0000u; return c.f;
}
__device__ __forceinline__ unsigned pack2(float a, float b) {
    return (unsigned)f2bf(a) | ((unsigned)f2bf(b) << 16);
}

// ================= utility =================

__global__ void zero_u32_kernel(unsigned* __restrict__ p, int n) {
    int i = blockIdx.x * blockDim.x + threadIdx.x;
    if (i < n) p[i] = 0u;
}

// zero phantom row N of both transposed y buffers: 8 slices x 4 words each
__global__ void zero_dummy_kernel(unsigned* __restrict__ a, unsigned* __restrict__ b,
                                  int N, int Np1) {
    int t = threadIdx.x;            // 64 threads
    int s = (t & 31) >> 2, w = t & 3;
    size_t off = ((size_t)s * Np1 + N) * 4 + w;
    if (t < 32) a[off] = 0u; else b[off] = 0u;
}

// ================= feature fusion =================
// writes bf16 x into totT (transposed) and bf16 y = dis*x into y0 (transposed)

__global__ void fuse_users_kernel(const float* __restrict__ feat,       // [U,15]
                                  const int* __restrict__ cidx,
                                  const int* __restrict__ sidx,
                                  const float* __restrict__ emb_w,      // [U,64]
                                  const float* __restrict__ Wn,         // [64,12]
                                  const float* __restrict__ bn,
                                  const float* __restrict__ Wv,         // [64,3]
                                  const float* __restrict__ bv,
                                  const float* __restrict__ color_w,    // [22,64]
                                  const float* __restrict__ size_w,     // [18,64]
                                  const float* __restrict__ dis,        // [N]
                                  unsigned short* __restrict__ totT,    // [8][N][8] bf16
                                  unsigned short* __restrict__ y0,      // [8][Np1][8] bf16
                                  int U, int N, int Np1) {
    int t = blockIdx.x * blockDim.x + threadIdx.x;
    int u = t >> 6, d = t & 63;
    if (u >= U) return;
    const float* f = feat + (size_t)u * 15;
    float acc = emb_w[(size_t)u * EMB + d] + bn[d] + bv[d];
#pragma unroll
    for (int k = 0; k < 12; ++k) acc = fmaf(f[k], Wn[d * 12 + k], acc);
#pragma unroll
    for (int k = 0; k < 3; ++k) acc = fmaf(f[12 + k], Wv[d * 3 + k], acc);
    acc += color_w[(size_t)cidx[u] * EMB + d];
    acc += size_w[(size_t)sidx[u] * EMB + d];
    int s = d >> 3, dd = d & 7;
    totT[((size_t)s * N + u) * 8 + dd] = f2bf(acc);
    y0[((size_t)s * Np1 + u) * 8 + dd] = f2bf(acc * dis[u]);
}

__global__ void fuse_items_kernel(const float* __restrict__ feat,       // [I,17]
                                  const float* __restrict__ emb_w,      // [I,64]
                                  const float* __restrict__ Wn,         // [64,5]
                                  const float* __restrict__ bn,
                                  const float* __restrict__ Wv,         // [64,12]
                                  const float* __restrict__ bv,
                                  const float* __restrict__ dis,        // [N]
                                  unsigned short* __restrict__ totT,
                                  unsigned short* __restrict__ y0,
                                  int I, int U, int N, int Np1) {
    int t = blockIdx.x * blockDim.x + threadIdx.x;
    int i = t >> 6, d = t & 63;
    if (i >= I) return;
    const float* f = feat + (size_t)i * 17;
    float acc = emb_w[(size_t)i * EMB + d] + bn[d] + bv[d];
#pragma unroll
    for (int k = 0; k < 5; ++k) acc = fmaf(f[k], Wn[d * 5 + k], acc);
#pragma unroll
    for (int k = 0; k < 12; ++k) acc = fmaf(f[5 + k], Wv[d * 12 + k], acc);
    int n = U + i;
    int s = d >> 3, dd = d & 7;
    totT[((size_t)s * N + n) * 8 + dd] = f2bf(acc);
    y0[((size_t)s * Np1 + n) * 8 + dd] = f2bf(acc * dis[n]);
}

// ================= bucketed CSR build =================
// pass 1: partition edges into NB col-range buckets (packed row<<9 | col&511)

__global__ __launch_bounds__(256) void partition_kernel(
        const int* __restrict__ row, const int* __restrict__ col,
        unsigned* __restrict__ bcursor, unsigned* __restrict__ bucketbuf,
        int E, int NB) {
    __shared__ unsigned h[NBMAX];
    __shared__ unsigned wbase[NBMAX];
    const int t = threadIdx.x;
    const long chunk = (long)blockIdx.x * BCAP;

    for (int i = t; i < NB; i += 256) h[i] = 0u;
    __syncthreads();
    for (int it = 0; it < BCAP / 256; ++it) {
        long e = chunk + (long)it * 256 + t;
        if (e < E) atomicAdd(&h[((unsigned)col[e]) >> 9], 1u);
    }
    __syncthreads();
    for (int i = t; i < NB; i += 256) {
        unsigned c = h[i];
        wbase[i] = c ? atomicAdd(&bcursor[i], c) : 0u;
    }
    __syncthreads();
    for (int i = t; i < NB; i += 256) h[i] = 0u;
    __syncthreads();
    for (int it = 0; it < BCAP / 256; ++it) {
        long e = chunk + (long)it * 256 + t;
        if (e < E) {
            unsigned c = (unsigned)col[e];
            unsigned b = c >> 9;
            unsigned lpos = atomicAdd(&h[b], 1u);
            unsigned pos = wbase[b] + lpos;
            if (pos < BCAP)
                bucketbuf[(size_t)b * BCAP + pos] = (((unsigned)row[e]) << 9) | (c & 511u);
        }
    }
}

// pass 2: one WG per bucket -> begs/ende (pad-8), dis, srcidx (+ phantom pads)

__global__ __launch_bounds__(256) void bucket_csr_kernel(
        const unsigned* __restrict__ bcursor,   // final per-bucket counts
        const unsigned* __restrict__ bucketbuf,
        unsigned* __restrict__ begs, unsigned* __restrict__ ende,
        float* __restrict__ dis, unsigned* __restrict__ srcidx,
        int N, int NB) {
    const int b = blockIdx.x;
    const int t = threadIdx.x;
    __shared__ unsigned hist[512];
    __shared__ unsigned ps[256];

    const unsigned base = (unsigned)b * BSTRIDE;
    unsigned cntb = bcursor[b];
    if (cntb > BCAP) cntb = BCAP;

    hist[2 * t] = 0u; hist[2 * t + 1] = 0u;
    __syncthreads();
    const unsigned* buf = bucketbuf + (size_t)b * BCAP;
    for (unsigned j = t; j < cntb; j += 256) atomicAdd(&hist[buf[j] & 511u], 1u);
    __syncthreads();

    unsigned h0 = hist[2 * t], h1 = hist[2 * t + 1];
    unsigned c0p = (h0 + 7u) & ~7u, c1p = (h1 + 7u) & ~7u;   // pad to multiple of 8
    ps[t] = c0p + c1p;
    __syncthreads();
    for (int off = 1; off < 256; off <<= 1) {
        unsigned y = (t >= off) ? ps[t - off] : 0u;
        __syncthreads();
        ps[t] += y;
        __syncthreads();
    }
    unsigned pexcl = ps[t] - (c0p + c1p);
    unsigned beg0 = base + pexcl, beg1 = beg0 + c0p;

    int n0 = (b << 9) + 2 * t, n1 = n0 + 1;
    if (n0 < N) {
        begs[n0] = beg0; ende[n0] = beg0 + c0p;
        dis[n0] = h0 ? rsqrtf((float)h0) : 0.f;
        for (unsigned k = h0; k < c0p; ++k) srcidx[beg0 + k] = (unsigned)N;  // phantom pads
    }
    if (n1 < N) {
        begs[n1] = beg1; ende[n1] = beg1 + c1p;
        dis[n1] = h1 ? rsqrtf((float)h1) : 0.f;
        for (unsigned k = h1; k < c1p; ++k) srcidx[beg1 + k] = (unsigned)N;
    }
    __syncthreads();

    // scatter via LDS cursors (absolute positions); writes stay in one bucket region
    hist[2 * t] = beg0; hist[2 * t + 1] = beg1;
    __syncthreads();
    for (unsigned j = t; j < cntb; j += 256) {
        unsigned p = buf[j];
        unsigned pos = atomicAdd(&hist[p & 511u], 1u);
        srcidx[pos] = p >> 9;
    }
}

// ================= propagation: dim-sliced, XCD-local =================
// slice s = blockIdx%8 -> XCD s (round-robin WG dispatch). Each slice's y
// region is 2.4 MB -> resident in that XCD's 4 MB L2. 8 lanes per node;
// lane l gathers the 16 B slice of edge j+l; butterfly-reduce the 8 lanes.

__global__ __launch_bounds__(256) void gather_slice_kernel(
        const unsigned* __restrict__ begs, const unsigned* __restrict__ ende,
        const float* __restrict__ dis,
        const unsigned* __restrict__ ysrc,     // [8][Np1][4] u32 (bf16x2)
        const unsigned* __restrict__ srcidx,
        unsigned* __restrict__ ynext,          // [8][Np1][4]
        unsigned* __restrict__ totT,           // [8][N][4] bf16x2 RMW
        int N, int Np1, int store) {
    const unsigned s = (unsigned)(blockIdx.x & 7);
    const int nb = (blockIdx.x >> 3) * 32;
    const int t = threadIdx.x;
    const int n = nb + (t >> 3);
    if (n >= N) return;
    const unsigned l = (unsigned)(t & 7);
    const unsigned* ybase = ysrc + (size_t)s * Np1 * 4;
    unsigned beg = begs[n], endp = ende[n];
    float s0 = 0.f, s1 = 0.f, s2 = 0.f, s3 = 0.f,
          s4 = 0.f, s5 = 0.f, s6 = 0.f, s7 = 0.f;
    for (unsigned j = beg + l; j < endp; j += 8) {
        unsigned r = srcidx[j];
        uint4 u = *reinterpret_cast<const uint4*>(ybase + (size_t)r * 4);
        s0 += bflo(u.x); s1 += bfhi(u.x);
        s2 += bflo(u.y); s3 += bfhi(u.y);
        s4 += bflo(u.z); s5 += bfhi(u.z);
        s6 += bflo(u.w); s7 += bfhi(u.w);
    }
    // reduce across the 8 lanes of this node's group
#pragma unroll
    for (int mask = 1; mask <= 4; mask <<= 1) {
        s0 += __shfl_xor(s0, mask); s1 += __shfl_xor(s1, mask);
        s2 += __shfl_xor(s2, mask); s3 += __shfl_xor(s3, mask);
        s4 += __shfl_xor(s4, mask); s5 += __shfl_xor(s5, mask);
        s6 += __shfl_xor(s6, mask); s7 += __shfl_xor(s7, mask);
    }
    float dn = dis[n];
    if (l == 0) {   // RMW running total (bf16)
        size_t o = ((size_t)s * N + n) * 4;
        uint4 tv = *reinterpret_cast<const uint4*>(totT + o);
        uint4 nv;
        nv.x = pack2(bflo(tv.x) + dn * s0, bfhi(tv.x) + dn * s1);
        nv.y = pack2(bflo(tv.y) + dn * s2, bfhi(tv.y) + dn * s3);
        nv.z = pack2(bflo(tv.z) + dn * s4, bfhi(tv.z) + dn * s5);
        nv.w = pack2(bflo(tv.w) + dn * s6, bfhi(tv.w) + dn * s7);
        *reinterpret_cast<uint4*>(totT + o) = nv;
    }
    if (store && l == 1) {   // next-layer y = dis * a = dn^2 * sum
        float d2 = dn * dn;
        size_t o = ((size_t)s * Np1 + n) * 4;
        uint4 pk;
        pk.x = pack2(d2 * s0, d2 * s1);
        pk.y = pack2(d2 * s2, d2 * s3);
        pk.z = pack2(d2 * s4, d2 * s5);
        pk.w = pack2(d2 * s6, d2 * s7);
        *reinterpret_cast<uint4*>(ynext + o) = pk;
    }
}

// ================= final untranspose: out[n][d] = totT[d>>3][n][d&7] / 4 ====

__global__ void untranspose_kernel(const unsigned* __restrict__ totT,
                                   float2* __restrict__ out2, int N) {
    int t = blockIdx.x * blockDim.x + threadIdx.x;
    int n = t >> 5;
    if (n >= N) return;
    unsigned w = (unsigned)(t & 31);          // dim-pair id; slice = w>>2, word = w&3
    unsigned u = totT[(((size_t)(w >> 2) * N + n) * 4) + (w & 3)];
    float2 v;
    v.x = bflo(u) * 0.25f;
    v.y = bfhi(u) * 0.25f;
    out2[(size_t)t] = v;                      // == out2[n*32 + w], coalesced
}

// ================= launch =================

extern "C" void kernel_launch(void* const* d_in, const int* in_sizes, int n_in,
                              void* d_out, int out_size, void* d_ws, size_t ws_size,
                              hipStream_t stream) {
    const int*   edge       = (const int*)d_in[0];
    const float* user_feat  = (const float*)d_in[1];
    const int*   cidx       = (const int*)d_in[2];
    const int*   sidx       = (const int*)d_in[3];
    const float* item_feat  = (const float*)d_in[4];
    const float* user_emb_w = (const float*)d_in[5];
    const float* item_emb_w = (const float*)d_in[6];
    const float* uWn        = (const float*)d_in[7];
    const float* ubn        = (const float*)d_in[8];
    const float* uWv        = (const float*)d_in[9];
    const float* ubv        = (const float*)d_in[10];
    const float* color_w    = (const float*)d_in[11];
    const float* size_w     = (const float*)d_in[12];
    const float* iWn        = (const float*)d_in[13];
    const float* ibn        = (const float*)d_in[14];
    const float* iWv        = (const float*)d_in[15];
    const float* ibv        = (const float*)d_in[16];

    const int E = in_sizes[0] / 2;
    const int U = in_sizes[5] / EMB;
    const int I = in_sizes[6] / EMB;
    const int N = U + I;
    const int Np1 = N + 1;
    const int NB = (N + 511) >> 9;     // 293 buckets

    const int* row = edge;
    const int* col = edge + E;

    // workspace layout (u32 units)
    unsigned* yA      = (unsigned*)d_ws;                    // [8*Np1*4] bf16x2 transposed
    unsigned* yB      = yA + (size_t)NSLICE * Np1 * 4;      // [8*Np1*4]
    unsigned* bucketbuf = yB;                               // [NB*BCAP] aliases yB (disjoint lifetime)
    unsigned* totT    = yB + (size_t)NSLICE * Np1 * 4;      // [8*N*4] bf16x2 transposed
    unsigned* srcidx  = totT + (size_t)NSLICE * N * 4;      // [NB*BSTRIDE]
    unsigned* begs    = srcidx + (size_t)NB * BSTRIDE;      // [N]
    unsigned* ende    = begs + N;                           // [N]
    float*    dis     = (float*)(ende + N);                 // [N]
    unsigned* bcursor = (unsigned*)(dis + N);               // [NB]

    const int TB = 256;

    // 1. CSR build (also produces dis)
    zero_u32_kernel<<<(NB + TB - 1) / TB, TB, 0, stream>>>(bcursor, NB);
    const int gP = (E + BCAP - 1) / BCAP;
    partition_kernel<<<gP, TB, 0, stream>>>(row, col, bcursor, bucketbuf, E, NB);
    bucket_csr_kernel<<<NB, TB, 0, stream>>>(bcursor, bucketbuf, begs, ende, dis,
                                             srcidx, N, NB);
    // phantom row N of both y buffers = 0 (after bucketbuf's lifetime ends)
    zero_dummy_kernel<<<1, 64, 0, stream>>>(yA, yB, N, Np1);

    // 2. fuse features -> totT (bf16 x), yA (bf16 dis*x), both transposed
    {
        int gU = (int)(((long)U * EMB + TB - 1) / TB);
        fuse_users_kernel<<<gU, TB, 0, stream>>>(user_feat, cidx, sidx, user_emb_w,
                                                 uWn, ubn, uWv, ubv, color_w, size_w,
                                                 dis, (unsigned short*)totT,
                                                 (unsigned short*)yA, U, N, Np1);
        int gI = (int)(((long)I * EMB + TB - 1) / TB);
        fuse_items_kernel<<<gI, TB, 0, stream>>>(item_feat, item_emb_w,
                                                 iWn, ibn, iWv, ibv,
                                                 dis, (unsigned short*)totT,
                                                 (unsigned short*)yA, I, U, N, Np1);
    }

    // 3. three propagation layers, slice-parallel (slice -> XCD), totT-accumulate fused
    const int gG = 8 * ((N + 31) / 32);
    gather_slice_kernel<<<gG, TB, 0, stream>>>(begs, ende, dis, yA, srcidx, yB, totT,
                                               N, Np1, 1);
    gather_slice_kernel<<<gG, TB, 0, stream>>>(begs, ende, dis, yB, srcidx, yA, totT,
                                               N, Np1, 1);
    gather_slice_kernel<<<gG, TB, 0, stream>>>(begs, ende, dis, yA, srcidx, yB, totT,
                                               N, Np1, 0);

    // 4. untranspose + /4 into d_out
    const long tU = (long)N * 32;
    untranspose_kernel<<<(int)((tU + TB - 1) / TB), TB, 0, stream>>>(totT,
                                                                     (float2*)d_out, N);

    (void)n_in; (void)out_size; (void)ws_size;
}

// Round 9
// 331.391 us; speedup vs baseline: 1.1972x; 1.1972x over previous
//
#include <hip/hip_runtime.h>

#define EMB 64
#define NBMAX 512      // max buckets (NB = ceil(N/512) = 293 for N=150000)
#define BCAP 8192      // bucket edge capacity (mean 6827, +16 sigma)
#define BSTRIDE 12288  // padded bucket region: BCAP + 512 nodes * 8 pad slots

// ---------------- bf16 helpers ----------------

__device__ __forceinline__ unsigned short f2bf(float f) {   // round-to-nearest-even
    union { float f; unsigned u; } c; c.f = f;
    unsigned r = c.u + 0x7fffu + ((c.u >> 16) & 1u);
    return (unsigned short)(r >> 16);
}
__device__ __forceinline__ float bflo(unsigned u) {         // low bf16 -> f32
    union { unsigned u; float f; } c; c.u = u << 16; return c.f;
}
__device__ __forceinline__ float bfhi(unsigned u) {         // high bf16 -> f32
    union { unsigned u; float f; } c; c.u = u & 0xffff0000u; return c.f;
}

// ================= utility =================

__global__ void zero_u32_kernel(unsigned* __restrict__ p, int n) {
    int i = blockIdx.x * blockDim.x + threadIdx.x;
    if (i < n) p[i] = 0u;
}

// zero the phantom row N of both y buffers (32 u32 words each)
__global__ void zero_dummy_kernel(unsigned* __restrict__ a, unsigned* __restrict__ b) {
    int t = threadIdx.x;
    if (t < 32) { a[t] = 0u; b[t] = 0u; }
}

// ================= feature fusion =================
// writes plain x into total (=d_out) and dis-premultiplied bf16 y into y0

__global__ void fuse_users_kernel(const float* __restrict__ feat,       // [U,15]
                                  const int* __restrict__ cidx,
                                  const int* __restrict__ sidx,
                                  const float* __restrict__ emb_w,      // [U,64]
                                  const float* __restrict__ Wn,         // [64,12]
                                  const float* __restrict__ bn,
                                  const float* __restrict__ Wv,         // [64,3]
                                  const float* __restrict__ bv,
                                  const float* __restrict__ color_w,    // [22,64]
                                  const float* __restrict__ size_w,     // [18,64]
                                  const float* __restrict__ dis,        // [N]
                                  float* __restrict__ total,            // [N,64]
                                  unsigned short* __restrict__ y0,      // [(N+1),64] bf16
                                  int U) {
    int t = blockIdx.x * blockDim.x + threadIdx.x;
    int u = t >> 6, d = t & 63;
    if (u >= U) return;
    const float* f = feat + (size_t)u * 15;
    float acc = emb_w[(size_t)u * EMB + d] + bn[d] + bv[d];
#pragma unroll
    for (int k = 0; k < 12; ++k) acc = fmaf(f[k], Wn[d * 12 + k], acc);
#pragma unroll
    for (int k = 0; k < 3; ++k) acc = fmaf(f[12 + k], Wv[d * 3 + k], acc);
    acc += color_w[(size_t)cidx[u] * EMB + d];
    acc += size_w[(size_t)sidx[u] * EMB + d];
    size_t o = (size_t)u * EMB + d;
    total[o] = acc;
    y0[o] = f2bf(acc * dis[u]);
}

__global__ void fuse_items_kernel(const float* __restrict__ feat,       // [I,17]
                                  const float* __restrict__ emb_w,      // [I,64]
                                  const float* __restrict__ Wn,         // [64,5]
                                  const float* __restrict__ bn,
                                  const float* __restrict__ Wv,         // [64,12]
                                  const float* __restrict__ bv,
                                  const float* __restrict__ dis,        // [N]
                                  float* __restrict__ total,
                                  unsigned short* __restrict__ y0,
                                  int I, int U) {
    int t = blockIdx.x * blockDim.x + threadIdx.x;
    int i = t >> 6, d = t & 63;
    if (i >= I) return;
    const float* f = feat + (size_t)i * 17;
    float acc = emb_w[(size_t)i * EMB + d] + bn[d] + bv[d];
#pragma unroll
    for (int k = 0; k < 5; ++k) acc = fmaf(f[k], Wn[d * 5 + k], acc);
#pragma unroll
    for (int k = 0; k < 12; ++k) acc = fmaf(f[5 + k], Wv[d * 12 + k], acc);
    int n = U + i;
    size_t o = (size_t)n * EMB + d;
    total[o] = acc;
    y0[o] = f2bf(acc * dis[n]);
}

// ================= bucketed CSR build =================
// pass 1: partition edges into NB col-range buckets (packed row<<9 | col&511)

__global__ __launch_bounds__(256) void partition_kernel(
        const int* __restrict__ row, const int* __restrict__ col,
        unsigned* __restrict__ bcursor, unsigned* __restrict__ bucketbuf,
        int E, int NB) {
    __shared__ unsigned h[NBMAX];
    __shared__ unsigned wbase[NBMAX];
    const int t = threadIdx.x;
    const long chunk = (long)blockIdx.x * BCAP;

    for (int i = t; i < NB; i += 256) h[i] = 0u;
    __syncthreads();
    for (int it = 0; it < BCAP / 256; ++it) {
        long e = chunk + (long)it * 256 + t;
        if (e < E) atomicAdd(&h[((unsigned)col[e]) >> 9], 1u);
    }
    __syncthreads();
    for (int i = t; i < NB; i += 256) {
        unsigned c = h[i];
        wbase[i] = c ? atomicAdd(&bcursor[i], c) : 0u;
    }
    __syncthreads();
    for (int i = t; i < NB; i += 256) h[i] = 0u;
    __syncthreads();
    for (int it = 0; it < BCAP / 256; ++it) {
        long e = chunk + (long)it * 256 + t;
        if (e < E) {
            unsigned c = (unsigned)col[e];
            unsigned b = c >> 9;
            unsigned lpos = atomicAdd(&h[b], 1u);
            unsigned pos = wbase[b] + lpos;
            if (pos < BCAP)
                bucketbuf[(size_t)b * BCAP + pos] = (((unsigned)row[e]) << 9) | (c & 511u);
        }
    }
}

// pass 2: one WG per bucket -> begs/ende (pad-8), dis, srcidx (+ phantom pads),
// plus per-degree-class node counts for the scheduling sort

__global__ __launch_bounds__(256) void bucket_csr_kernel(
        const unsigned* __restrict__ bcursor,   // final per-bucket counts
        const unsigned* __restrict__ bucketbuf,
        unsigned* __restrict__ begs, unsigned* __restrict__ ende,
        float* __restrict__ dis, unsigned* __restrict__ srcidx,
        unsigned* __restrict__ clsCnt,          // [64] global degree-class counts
        int N, int NB) {
    const int b = blockIdx.x;
    const int t = threadIdx.x;
    __shared__ unsigned hist[512];
    __shared__ unsigned ps[256];
    __shared__ unsigned cls[64];

    const unsigned base = (unsigned)b * BSTRIDE;
    unsigned cntb = bcursor[b];
    if (cntb > BCAP) cntb = BCAP;

    hist[2 * t] = 0u; hist[2 * t + 1] = 0u;
    if (t < 64) cls[t] = 0u;
    __syncthreads();
    const unsigned* buf = bucketbuf + (size_t)b * BCAP;
    for (unsigned j = t; j < cntb; j += 256) atomicAdd(&hist[buf[j] & 511u], 1u);
    __syncthreads();

    unsigned h0 = hist[2 * t], h1 = hist[2 * t + 1];
    unsigned c0p = (h0 + 7u) & ~7u, c1p = (h1 + 7u) & ~7u;   // pad to multiple of 8
    ps[t] = c0p + c1p;
    __syncthreads();
    for (int off = 1; off < 256; off <<= 1) {
        unsigned y = (t >= off) ? ps[t - off] : 0u;
        __syncthreads();
        ps[t] += y;
        __syncthreads();
    }
    unsigned pexcl = ps[t] - (c0p + c1p);
    unsigned beg0 = base + pexcl, beg1 = beg0 + c0p;

    int n0 = (b << 9) + 2 * t, n1 = n0 + 1;
    if (n0 < N) {
        begs[n0] = beg0; ende[n0] = beg0 + c0p;
        dis[n0] = h0 ? rsqrtf((float)h0) : 0.f;
        atomicAdd(&cls[min(c0p >> 3, 63u)], 1u);
        for (unsigned k = h0; k < c0p; ++k) srcidx[beg0 + k] = (unsigned)N;  // phantom pads
    }
    if (n1 < N) {
        begs[n1] = beg1; ende[n1] = beg1 + c1p;
        dis[n1] = h1 ? rsqrtf((float)h1) : 0.f;
        atomicAdd(&cls[min(c1p >> 3, 63u)], 1u);
        for (unsigned k = h1; k < c1p; ++k) srcidx[beg1 + k] = (unsigned)N;
    }
    __syncthreads();

    // flush class counts; repurpose hist as scatter cursors
    if (t < 64 && cls[t]) atomicAdd(&clsCnt[t], cls[t]);
    hist[2 * t] = beg0; hist[2 * t + 1] = beg1;
    __syncthreads();
    for (unsigned j = t; j < cntb; j += 256) {
        unsigned p = buf[j];
        unsigned pos = atomicAdd(&hist[p & 511u], 1u);
        srcidx[pos] = p >> 9;
    }
}

// exclusive scan of the 64 class counts -> clsBase

__global__ void cls_scan_kernel(const unsigned* __restrict__ clsCnt,
                                unsigned* __restrict__ clsBase) {
    __shared__ unsigned sh[64];
    int t = threadIdx.x;
    if (t < 64) sh[t] = clsCnt[t];
    __syncthreads();
    if (t == 0) {
        unsigned run = 0;
        for (int i = 0; i < 64; ++i) { unsigned v = sh[i]; sh[i] = run; run += v; }
    }
    __syncthreads();
    if (t < 64) clsBase[t] = sh[t];
}

// counting-sort node ids by degree class into order[] (LDS-aggregated)

__global__ __launch_bounds__(256) void order_fill_kernel(
        const unsigned* __restrict__ begs, const unsigned* __restrict__ ende,
        const unsigned* __restrict__ clsBase, unsigned* __restrict__ clsCur,
        unsigned* __restrict__ order, int N) {
    __shared__ unsigned h[64], wb[64];
    int t = threadIdx.x;
    int n = blockIdx.x * 256 + t;
    if (t < 64) h[t] = 0u;
    __syncthreads();
    unsigned c = 0, lpos = 0;
    bool valid = n < N;
    if (valid) {
        unsigned deg = ende[n] - begs[n];
        c = min(deg >> 3, 63u);
        lpos = atomicAdd(&h[c], 1u);
    }
    __syncthreads();
    if (t < 64) wb[t] = h[t] ? atomicAdd(&clsCur[t], h[t]) : 0u;
    __syncthreads();
    if (valid) order[clsBase[c] + wb[c] + lpos] = (unsigned)n;
}

// ================= propagation =================
// y rows viewed as 32 u32 words (bf16x2). One wave per node (degree-sorted via
// order[]). lane = (q, m): q = lane>>4 picks edge within each idx-quad, m =
// lane&15 covers dims 4m..4m+3 via one uint2 load -> one wave-load covers FOUR
// rows. 16-edge unrolled main loop (4 idx quads + 16 row loads in flight) +
// 8-edge tail. All loads/stores cacheable (L2/L3 keeps inter-layer data).

__global__ __launch_bounds__(256) void gather_propagate_kernel(
        const unsigned* __restrict__ order,
        const unsigned* __restrict__ begs, const unsigned* __restrict__ ende,
        const float* __restrict__ dis, const unsigned* __restrict__ src,   // [(N+1)*32]
        const unsigned* __restrict__ srcidx,
        unsigned* __restrict__ ynext,      // [(N+1)*32]
        float4* __restrict__ total4,       // [N*16]
        float scale, int N, int store) {
    int slot = blockIdx.x * 4 + (threadIdx.x >> 6);
    if (slot >= N) return;
    int n = (int)order[slot];
    int lane = threadIdx.x & 63;
    unsigned q = (unsigned)(lane >> 4);
    unsigned m = (unsigned)(lane & 15);
    unsigned beg = begs[n], endp = ende[n];
    float dn = dis[n];
    float s0 = 0.f, s1 = 0.f, s2 = 0.f, s3 = 0.f;
    unsigned j = beg;
    for (; j + 16 <= endp; j += 16) {
        uint4 ia = *reinterpret_cast<const uint4*>(&srcidx[j]);
        uint4 ib = *reinterpret_cast<const uint4*>(&srcidx[j + 4]);
        uint4 ic = *reinterpret_cast<const uint4*>(&srcidx[j + 8]);
        uint4 id = *reinterpret_cast<const uint4*>(&srcidx[j + 12]);
        unsigned ra = q == 0 ? ia.x : (q == 1 ? ia.y : (q == 2 ? ia.z : ia.w));
        unsigned rb = q == 0 ? ib.x : (q == 1 ? ib.y : (q == 2 ? ib.z : ib.w));
        unsigned rc = q == 0 ? ic.x : (q == 1 ? ic.y : (q == 2 ? ic.z : ic.w));
        unsigned rd = q == 0 ? id.x : (q == 1 ? id.y : (q == 2 ? id.z : id.w));
        uint2 ua = *reinterpret_cast<const uint2*>(&src[ra * 32u + 2u * m]);
        uint2 ub = *reinterpret_cast<const uint2*>(&src[rb * 32u + 2u * m]);
        uint2 uc = *reinterpret_cast<const uint2*>(&src[rc * 32u + 2u * m]);
        uint2 ud = *reinterpret_cast<const uint2*>(&src[rd * 32u + 2u * m]);
        s0 += (bflo(ua.x) + bflo(ub.x)) + (bflo(uc.x) + bflo(ud.x));
        s1 += (bfhi(ua.x) + bfhi(ub.x)) + (bfhi(uc.x) + bfhi(ud.x));
        s2 += (bflo(ua.y) + bflo(ub.y)) + (bflo(uc.y) + bflo(ud.y));
        s3 += (bfhi(ua.y) + bfhi(ub.y)) + (bfhi(uc.y) + bfhi(ud.y));
    }
    if (j < endp) {   // 8-edge tail (lists are multiples of 8)
        uint4 ia = *reinterpret_cast<const uint4*>(&srcidx[j]);
        uint4 ib = *reinterpret_cast<const uint4*>(&srcidx[j + 4]);
        unsigned ra = q == 0 ? ia.x : (q == 1 ? ia.y : (q == 2 ? ia.z : ia.w));
        unsigned rb = q == 0 ? ib.x : (q == 1 ? ib.y : (q == 2 ? ib.z : ib.w));
        uint2 ua = *reinterpret_cast<const uint2*>(&src[ra * 32u + 2u * m]);
        uint2 ub = *reinterpret_cast<const uint2*>(&src[rb * 32u + 2u * m]);
        s0 += bflo(ua.x) + bflo(ub.x);
        s1 += bfhi(ua.x) + bfhi(ub.x);
        s2 += bflo(ua.y) + bflo(ub.y);
        s3 += bfhi(ua.y) + bfhi(ub.y);
    }
    // combine the four slot-parity groups
    s0 += __shfl_xor(s0, 16); s0 += __shfl_xor(s0, 32);
    s1 += __shfl_xor(s1, 16); s1 += __shfl_xor(s1, 32);
    s2 += __shfl_xor(s2, 16); s2 += __shfl_xor(s2, 32);
    s3 += __shfl_xor(s3, 16); s3 += __shfl_xor(s3, 32);
    if (lane < 16) {
        float a0 = dn * s0, a1 = dn * s1, a2 = dn * s2, a3 = dn * s3;
        size_t o4 = (size_t)n * 16 + m;
        float4 tv = total4[o4];
        total4[o4] = make_float4((tv.x + a0) * scale, (tv.y + a1) * scale,
                                 (tv.z + a2) * scale, (tv.w + a3) * scale);
        if (store) {
            uint2 pk;
            pk.x = (unsigned)f2bf(dn * a0) | ((unsigned)f2bf(dn * a1) << 16);
            pk.y = (unsigned)f2bf(dn * a2) | ((unsigned)f2bf(dn * a3) << 16);
            *reinterpret_cast<uint2*>(&ynext[(size_t)n * 32 + 2u * m]) = pk;
        }
    }
}

// ================= launch =================

extern "C" void kernel_launch(void* const* d_in, const int* in_sizes, int n_in,
                              void* d_out, int out_size, void* d_ws, size_t ws_size,
                              hipStream_t stream) {
    const int*   edge       = (const int*)d_in[0];
    const float* user_feat  = (const float*)d_in[1];
    const int*   cidx       = (const int*)d_in[2];
    const int*   sidx       = (const int*)d_in[3];
    const float* item_feat  = (const float*)d_in[4];
    const float* user_emb_w = (const float*)d_in[5];
    const float* item_emb_w = (const float*)d_in[6];
    const float* uWn        = (const float*)d_in[7];
    const float* ubn        = (const float*)d_in[8];
    const float* uWv        = (const float*)d_in[9];
    const float* ubv        = (const float*)d_in[10];
    const float* color_w    = (const float*)d_in[11];
    const float* size_w     = (const float*)d_in[12];
    const float* iWn        = (const float*)d_in[13];
    const float* ibn        = (const float*)d_in[14];
    const float* iWv        = (const float*)d_in[15];
    const float* ibv        = (const float*)d_in[16];

    const int E = in_sizes[0] / 2;
    const int U = in_sizes[5] / EMB;
    const int I = in_sizes[6] / EMB;
    const int N = U + I;
    const int NB = (N + 511) >> 9;     // 293 buckets

    const int* row = edge;
    const int* col = edge + E;

    float* total = (float*)d_out;      // running sum x + a1 + a2 + a3

    // workspace layout (u32 units)
    unsigned short* yA      = (unsigned short*)d_ws;          // [(N+1)*64] bf16
    unsigned short* yB      = yA + (size_t)(N + 1) * EMB;     // [(N+1)*64] bf16
    unsigned*       bucketbuf = (unsigned*)yB;                // [NB*BCAP] aliases yB (disjoint lifetime)
    unsigned*       srcidx  = (unsigned*)(yB + (size_t)(N + 1) * EMB);  // [NB*BSTRIDE]
    unsigned*       begs    = srcidx + (size_t)NB * BSTRIDE;  // [N]
    unsigned*       ende    = begs + N;                       // [N]
    float*          dis     = (float*)(ende + N);             // [N]
    unsigned*       bcursor = (unsigned*)(dis + N);           // [NB]
    unsigned*       clsCnt  = bcursor + NB;                   // [64]
    unsigned*       clsCur  = clsCnt + 64;                    // [64]
    unsigned*       clsBase = clsCur + 64;                    // [64]
    unsigned*       order   = clsBase + 64;                   // [N]

    const int TB = 256;

    // 1. CSR build (also produces dis + degree-class counts)
    zero_u32_kernel<<<(NB + 128 + TB - 1) / TB, TB, 0, stream>>>(bcursor, NB + 128);
    const int gP = (E + BCAP - 1) / BCAP;
    partition_kernel<<<gP, TB, 0, stream>>>(row, col, bcursor, bucketbuf, E, NB);
    bucket_csr_kernel<<<NB, TB, 0, stream>>>(bcursor, bucketbuf, begs, ende, dis,
                                             srcidx, clsCnt, N, NB);
    // degree-class scheduling order
    cls_scan_kernel<<<1, 64, 0, stream>>>(clsCnt, clsBase);
    order_fill_kernel<<<(N + TB - 1) / TB, TB, 0, stream>>>(begs, ende, clsBase,
                                                            clsCur, order, N);
    // phantom row N of both y buffers = 0 (after bucketbuf's lifetime ends)
    zero_dummy_kernel<<<1, 64, 0, stream>>>((unsigned*)(yA + (size_t)N * EMB),
                                            (unsigned*)(yB + (size_t)N * EMB));

    // 2. fuse features: total = x, yA = bf16(dis*x)
    {
        int gU = (int)(((long)U * EMB + TB - 1) / TB);
        fuse_users_kernel<<<gU, TB, 0, stream>>>(user_feat, cidx, sidx, user_emb_w,
                                                 uWn, ubn, uWv, ubv, color_w, size_w,
                                                 dis, total, yA, U);
        int gI = (int)(((long)I * EMB + TB - 1) / TB);
        fuse_items_kernel<<<gI, TB, 0, stream>>>(item_feat, item_emb_w,
                                                 iWn, ibn, iWv, ibv,
                                                 dis, total, yA, I, U);
    }

    // 3. three propagation layers (gather form), total-accumulate fused
    const int gG = (N + 3) / 4;   // 4 degree-matched waves per block
    gather_propagate_kernel<<<gG, TB, 0, stream>>>(order, begs, ende, dis,
                                                   (const unsigned*)yA, srcidx,
                                                   (unsigned*)yB, (float4*)total,
                                                   1.0f, N, 1);
    gather_propagate_kernel<<<gG, TB, 0, stream>>>(order, begs, ende, dis,
                                                   (const unsigned*)yB, srcidx,
                                                   (unsigned*)yA, (float4*)total,
                                                   1.0f, N, 1);
    gather_propagate_kernel<<<gG, TB, 0, stream>>>(order, begs, ende, dis,
                                                   (const unsigned*)yA, srcidx,
                                                   (unsigned*)yB, (float4*)total,
                                                   0.25f, N, 0);

    (void)n_in; (void)out_size; (void)ws_size;
}